// Round 1
// baseline (539.200 us; speedup 1.0000x reference)
//
#include <hip/hip_runtime.h>

// Problem constants
#define B_ 128
#define T_ 197
#define D_ 768
#define E_ 8
#define R_ 8
#define O_ 2304

// d_out flat layout (fp32 elements), in reference return order
#define NWU      (128LL * 197LL * 2304LL)      // weighted_update: 58,097,664
#define OFF_RL   (NWU)                          // router_logits: 128*8
#define OFF_SEL  (OFF_RL + 128LL * 8LL)         // selected_experts: 128 (stored as float)
#define OFF_EW   (OFF_SEL + 128LL)              // expert_weights: 128*8
#define OFF_IMP  (OFF_EW + 128LL * 8LL)         // importance: 8
#define OFF_LOAD (OFF_IMP + 8LL)                // load: 8

// ---------------------------------------------------------------------------
// Kernel 1: partial token sums over T-chunks.
// Writes partials into the weighted_update region of d_out (overwritten later
// by moe_main, after `route` has consumed them).  part[(b*4+c)*768 + d]
// ---------------------------------------------------------------------------
__global__ void pool_partial(const float* __restrict__ tokens,
                             float* __restrict__ out) {
    int c   = blockIdx.x;          // 0..3
    int b   = blockIdx.y;          // 0..127
    int tid = threadIdx.x;         // 0..255
    int t0 = c * 50;
    int t1 = t0 + 50; if (t1 > T_) t1 = T_;
    const float* tp = tokens + (long long)b * T_ * D_;
    float a0 = 0.f, a1 = 0.f, a2 = 0.f;
    for (int t = t0; t < t1; ++t) {
        const float* row = tp + (long long)t * D_;
        a0 += row[tid];
        a1 += row[tid + 256];
        a2 += row[tid + 512];
    }
    float* p = out + (long long)(b * 4 + c) * D_;
    p[tid]       = a0;
    p[tid + 256] = a1;
    p[tid + 512] = a2;
}

// ---------------------------------------------------------------------------
// Kernel 2: routing.  One block per batch row.
// pooled = (sum of 4 partials)/197 ; logits = pooled @ w_gate ; softmax/argmax
// Writes router_logits, selected_experts (float), expert_weights.
// ---------------------------------------------------------------------------
__global__ void route(const float* __restrict__ part,
                      const float* __restrict__ w_gate,
                      float* __restrict__ out) {
    __shared__ float pooled[768];
    __shared__ float psum[64];
    __shared__ float logits[8];
    __shared__ int   sel_s;
    __shared__ float top1_s;

    int b   = blockIdx.x;
    int tid = threadIdx.x;

    #pragma unroll
    for (int j = 0; j < 3; ++j) {
        int d = tid + j * 256;
        float s = part[(long long)(b * 4 + 0) * D_ + d]
                + part[(long long)(b * 4 + 1) * D_ + d]
                + part[(long long)(b * 4 + 2) * D_ + d]
                + part[(long long)(b * 4 + 3) * D_ + d];
        pooled[d] = s * (1.0f / 197.0f);
    }
    __syncthreads();

    if (tid < 64) {
        int e = tid & 7;
        int p = tid >> 3;
        float s = 0.f;
        int d0 = p * 96;
        for (int d = d0; d < d0 + 96; ++d) s += pooled[d] * w_gate[d * 8 + e];
        psum[tid] = s;
    }
    __syncthreads();

    if (tid < 8) {
        float s = 0.f;
        #pragma unroll
        for (int p = 0; p < 8; ++p) s += psum[p * 8 + tid];
        logits[tid] = s;
        out[OFF_RL + (long long)b * 8 + tid] = s;
    }
    __syncthreads();

    if (tid == 0) {
        float m = logits[0];
        int sel = 0;
        #pragma unroll
        for (int e = 1; e < 8; ++e)
            if (logits[e] > m) { m = logits[e]; sel = e; }   // first max wins
        float den = 0.f;
        #pragma unroll
        for (int e = 0; e < 8; ++e) den += expf(logits[e] - m);
        sel_s  = sel;
        top1_s = 1.0f / den;                                  // exp(0)/den
        out[OFF_SEL + b] = (float)sel;
    }
    __syncthreads();

    if (tid < 8)
        out[OFF_EW + (long long)b * 8 + tid] = (tid == sel_s) ? top1_s : 0.0f;
}

// ---------------------------------------------------------------------------
// Kernel 3: stats.  One block.  importance = sum_b expert_weights;
// load = sum_b softmax(router_logits).
// ---------------------------------------------------------------------------
__global__ void stats(float* __restrict__ out) {
    __shared__ float loadacc[8];
    int tid = threadIdx.x;   // 0..127 = batch index
    if (tid < 8) loadacc[tid] = 0.0f;
    __syncthreads();

    float l[8];
    float m = -1e30f;
    #pragma unroll
    for (int e = 0; e < 8; ++e) {
        l[e] = out[OFF_RL + (long long)tid * 8 + e];
        m = fmaxf(m, l[e]);
    }
    float den = 0.f;
    #pragma unroll
    for (int e = 0; e < 8; ++e) { l[e] = expf(l[e] - m); den += l[e]; }
    float inv = 1.0f / den;
    #pragma unroll
    for (int e = 0; e < 8; ++e) atomicAdd(&loadacc[e], l[e] * inv);
    __syncthreads();

    if (tid < 8) {
        out[OFF_LOAD + tid] = loadacc[tid];
        float s = 0.f;
        for (int b = 0; b < 128; ++b) s += out[OFF_EW + (long long)b * 8 + tid];
        out[OFF_IMP + tid] = s;
    }
}

// ---------------------------------------------------------------------------
// Kernel 4: main LoRA compute.
// Grid (chunk=4, b=128), 256 threads (4 waves).  Bw[sel] staged in LDS (72 KB
// -> 2 blocks/CU).  A[sel] (24 KB) read from global, L1-resident.
// Wave-per-row: lane accumulates h[0..8) over its 12 d's, 64-lane butterfly
// reduce, gate_scale folded into h, 9 float4 outputs per lane per row.
// ---------------------------------------------------------------------------
__global__ void __launch_bounds__(256, 2)
moe_main(const float* __restrict__ tokens,
         const float* __restrict__ lora_a,
         const float* __restrict__ lora_b,
         const float* __restrict__ scaling,
         float* __restrict__ out) {
    __shared__ __align__(16) float Bw_s[8 * 2304];

    int chunk = blockIdx.x;
    int b     = blockIdx.y;
    int tid   = threadIdx.x;

    int   sel  = (int)out[OFF_SEL + b];
    float top1 = out[OFF_EW + (long long)b * 8 + sel];
    float gs   = scaling[sel] * top1;

    // Stage Bw[sel] (8 x 2304) into LDS, float4 copies.
    const float4* Bw4g = (const float4*)(lora_b + (long long)sel * 8 * 2304);
    float4*       Bw4s = (float4*)Bw_s;
    for (int i = tid; i < 8 * 576; i += 256) Bw4s[i] = Bw4g[i];
    __syncthreads();

    const float* Ap = lora_a + (long long)sel * 768 * 8;   // [d][r], 24 KB

    int wave = tid >> 6;
    int lane = tid & 63;
    int t0 = chunk * 50;
    int t1 = t0 + 50; if (t1 > T_) t1 = T_;

    for (int t = t0 + wave; t < t1; t += 4) {
        const float4* tok4 = (const float4*)(tokens + ((long long)b * T_ + t) * D_);
        float acc[8];
        #pragma unroll
        for (int r = 0; r < 8; ++r) acc[r] = 0.f;

        #pragma unroll
        for (int k = 0; k < 3; ++k) {
            int   d4 = lane + 64 * k;                 // float4 index into token row
            float4 tv = tok4[d4];
            const float4* A4 = (const float4*)(Ap + (long long)d4 * 32);  // 4 d's x 8 r
            float4 a0 = A4[0], a1 = A4[1], a2 = A4[2], a3 = A4[3];
            float4 a4 = A4[4], a5 = A4[5], a6 = A4[6], a7 = A4[7];
            acc[0] += tv.x * a0.x; acc[1] += tv.x * a0.y; acc[2] += tv.x * a0.z; acc[3] += tv.x * a0.w;
            acc[4] += tv.x * a1.x; acc[5] += tv.x * a1.y; acc[6] += tv.x * a1.z; acc[7] += tv.x * a1.w;
            acc[0] += tv.y * a2.x; acc[1] += tv.y * a2.y; acc[2] += tv.y * a2.z; acc[3] += tv.y * a2.w;
            acc[4] += tv.y * a3.x; acc[5] += tv.y * a3.y; acc[6] += tv.y * a3.z; acc[7] += tv.y * a3.w;
            acc[0] += tv.z * a4.x; acc[1] += tv.z * a4.y; acc[2] += tv.z * a4.z; acc[3] += tv.z * a4.w;
            acc[4] += tv.z * a5.x; acc[5] += tv.z * a5.y; acc[6] += tv.z * a5.z; acc[7] += tv.z * a5.w;
            acc[0] += tv.w * a6.x; acc[1] += tv.w * a6.y; acc[2] += tv.w * a6.z; acc[3] += tv.w * a6.w;
            acc[4] += tv.w * a7.x; acc[5] += tv.w * a7.y; acc[6] += tv.w * a7.z; acc[7] += tv.w * a7.w;
        }

        // 64-lane butterfly reduce; result broadcast to all lanes.
        #pragma unroll
        for (int off = 32; off > 0; off >>= 1) {
            #pragma unroll
            for (int r = 0; r < 8; ++r)
                acc[r] += __shfl_xor(acc[r], off, 64);
        }

        float hg[8];
        #pragma unroll
        for (int r = 0; r < 8; ++r) hg[r] = acc[r] * gs;

        float4* outrow = (float4*)(out + ((long long)b * T_ + t) * O_);
        #pragma unroll
        for (int k = 0; k < 9; ++k) {
            int o4 = lane + 64 * k;
            float4 v; v.x = 0.f; v.y = 0.f; v.z = 0.f; v.w = 0.f;
            #pragma unroll
            for (int r = 0; r < 8; ++r) {
                float4 bv = ((const float4*)(Bw_s + r * 2304))[o4];
                v.x += hg[r] * bv.x;
                v.y += hg[r] * bv.y;
                v.z += hg[r] * bv.z;
                v.w += hg[r] * bv.w;
            }
            outrow[o4] = v;
        }
    }
}

// ---------------------------------------------------------------------------
extern "C" void kernel_launch(void* const* d_in, const int* in_sizes, int n_in,
                              void* d_out, int out_size, void* d_ws, size_t ws_size,
                              hipStream_t stream) {
    const float* tokens  = (const float*)d_in[0];
    const float* w_gate  = (const float*)d_in[1];
    const float* lora_a  = (const float*)d_in[2];
    const float* lora_b  = (const float*)d_in[3];
    const float* scaling = (const float*)d_in[4];
    float* out = (float*)d_out;

    // 1) partial pooling sums (into WU scratch region of d_out)
    pool_partial<<<dim3(4, 128), 256, 0, stream>>>(tokens, out);
    // 2) routing (consumes partials, writes RL/SEL/EW)
    route<<<128, 256, 0, stream>>>(out, w_gate, out);
    // 3) importance + load
    stats<<<1, 128, 0, stream>>>(out);
    // 4) main compute (overwrites WU region with real output)
    moe_main<<<dim3(4, 128), 256, 0, stream>>>(tokens, lora_a, lora_b, scaling, out);
}

// Round 3
// 457.839 us; speedup vs baseline: 1.1777x; 1.1777x over previous
//
#include <hip/hip_runtime.h>

typedef float v4f __attribute__((ext_vector_type(4)));

// Problem constants
#define B_ 128
#define T_ 197
#define D_ 768
#define E_ 8
#define R_ 8
#define O_ 2304

// d_out flat layout (fp32 elements), in reference return order
#define NWU      (128LL * 197LL * 2304LL)      // weighted_update
#define OFF_RL   (NWU)                          // router_logits: 128*8
#define OFF_SEL  (OFF_RL + 1024LL)              // selected_experts: 128 (as float)
#define OFF_EW   (OFF_SEL + 128LL)              // expert_weights: 128*8
#define OFF_IMP  (OFF_EW + 1024LL)              // importance: 8
#define OFF_LOAD (OFF_IMP + 8LL)                // load: 8

// ---------------------------------------------------------------------------
// Kernel 1: partial token sums over T-chunks, float4-vectorized.
// partials live in the WU region of d_out (consumed by `route` before
// lora_out overwrites the region).  part[(b*4+c)*768 + d]
// ---------------------------------------------------------------------------
__global__ void pool_partial(const float* __restrict__ tokens,
                             float* __restrict__ out) {
    int c   = blockIdx.x;          // 0..3
    int b   = blockIdx.y;          // 0..127
    int tid = threadIdx.x;         // 0..191  (float4 column)
    int t0 = c * 50;
    int t1 = t0 + 50; if (t1 > T_) t1 = T_;
    const float4* tp = (const float4*)(tokens + (long long)b * T_ * D_);
    float4 acc; acc.x = 0.f; acc.y = 0.f; acc.z = 0.f; acc.w = 0.f;
    for (int t = t0; t < t1; ++t) {
        float4 v = tp[t * 192 + tid];
        acc.x += v.x; acc.y += v.y; acc.z += v.z; acc.w += v.w;
    }
    ((float4*)out)[(long long)(b * 4 + c) * 192 + tid] = acc;
}

// ---------------------------------------------------------------------------
// Kernel 2: routing.  One block per batch row.
// ---------------------------------------------------------------------------
__global__ void route(const float* __restrict__ part,
                      const float* __restrict__ w_gate,
                      float* __restrict__ out) {
    __shared__ float pooled[768];
    __shared__ float psum[64];
    __shared__ float logits[8];
    __shared__ int   sel_s;
    __shared__ float top1_s;

    int b   = blockIdx.x;
    int tid = threadIdx.x;

    #pragma unroll
    for (int j = 0; j < 3; ++j) {
        int d = tid + j * 256;
        float s = part[(long long)(b * 4 + 0) * D_ + d]
                + part[(long long)(b * 4 + 1) * D_ + d]
                + part[(long long)(b * 4 + 2) * D_ + d]
                + part[(long long)(b * 4 + 3) * D_ + d];
        pooled[d] = s * (1.0f / 197.0f);
    }
    __syncthreads();

    if (tid < 64) {
        int e = tid & 7;
        int p = tid >> 3;
        float s = 0.f;
        int d0 = p * 96;
        for (int d = d0; d < d0 + 96; ++d) s += pooled[d] * w_gate[d * 8 + e];
        psum[tid] = s;
    }
    __syncthreads();

    if (tid < 8) {
        float s = 0.f;
        #pragma unroll
        for (int p = 0; p < 8; ++p) s += psum[p * 8 + tid];
        logits[tid] = s;
        out[OFF_RL + (long long)b * 8 + tid] = s;
    }
    __syncthreads();

    if (tid == 0) {
        float m = logits[0];
        int sel = 0;
        #pragma unroll
        for (int e = 1; e < 8; ++e)
            if (logits[e] > m) { m = logits[e]; sel = e; }   // first max wins
        float den = 0.f;
        #pragma unroll
        for (int e = 0; e < 8; ++e) den += expf(logits[e] - m);
        sel_s  = sel;
        top1_s = 1.0f / den;
        out[OFF_SEL + b] = (float)sel;
    }
    __syncthreads();

    if (tid < 8)
        out[OFF_EW + (long long)b * 8 + tid] = (tid == sel_s) ? top1_s : 0.0f;
}

// ---------------------------------------------------------------------------
// Kernel 3: stats (parallel).  importance = sum_b ew; load = sum_b softmax(rl)
// ---------------------------------------------------------------------------
__global__ void stats(float* __restrict__ out) {
    __shared__ float accI[8], accL[8];
    int tid = threadIdx.x;   // 0..127 = batch index
    if (tid < 8) { accI[tid] = 0.f; accL[tid] = 0.f; }
    __syncthreads();

    float l[8];
    float m = -1e30f;
    #pragma unroll
    for (int e = 0; e < 8; ++e) {
        l[e] = out[OFF_RL + (long long)tid * 8 + e];
        m = fmaxf(m, l[e]);
    }
    float den = 0.f;
    #pragma unroll
    for (int e = 0; e < 8; ++e) { l[e] = expf(l[e] - m); den += l[e]; }
    float inv = 1.0f / den;
    #pragma unroll
    for (int e = 0; e < 8; ++e) {
        atomicAdd(&accL[e], l[e] * inv);
        atomicAdd(&accI[e], out[OFF_EW + (long long)tid * 8 + e]);
    }
    __syncthreads();

    if (tid < 8) {
        out[OFF_LOAD + tid] = accL[tid];
        out[OFF_IMP + tid]  = accI[tid];
    }
}

// ---------------------------------------------------------------------------
// Kernel 4: h = (tokens @ A[sel]) * gate_scale  →  d_ws  (128*197*8 floats)
// A staged TRANSPOSED in LDS: As[r][d] so lane reads are 16B-stride b128,
// conflict-free.  This kills the 614 MB A-refetch from round 1.
// ---------------------------------------------------------------------------
__global__ void lora_h(const float* __restrict__ tokens,
                       const float* __restrict__ lora_a,
                       const float* __restrict__ scaling,
                       const float* __restrict__ outc,
                       float* __restrict__ hws) {
    __shared__ float As[8 * 768];   // 24 KB

    int chunk = blockIdx.x;
    int b     = blockIdx.y;
    int tid   = threadIdx.x;

    int   sel  = (int)outc[OFF_SEL + b];
    float top1 = outc[OFF_EW + (long long)b * 8 + sel];
    float gs   = scaling[sel] * top1;

    // Stage A[sel] (layout [d][r]) transposed into As[r][d].
    const float4* A4 = (const float4*)(lora_a + (long long)sel * 768 * 8);
    for (int f = tid; f < 1536; f += 256) {
        float4 g = A4[f];
        int d  = f >> 1;
        int r0 = (f & 1) * 4;
        As[(r0 + 0) * 768 + d] = g.x;
        As[(r0 + 1) * 768 + d] = g.y;
        As[(r0 + 2) * 768 + d] = g.z;
        As[(r0 + 3) * 768 + d] = g.w;
    }
    __syncthreads();

    int wave = tid >> 6;
    int lane = tid & 63;
    int t0 = chunk * 50;
    int t1 = t0 + 50; if (t1 > T_) t1 = T_;
    int nr  = t1 - t0;
    int rpw = (nr + 3) >> 2;
    int ts  = t0 + wave * rpw;
    int te  = ts + rpw; if (te > t1) te = t1;

    for (int t = ts; t < te; ++t) {
        const float4* tok4 = (const float4*)(tokens + ((long long)b * T_ + t) * D_);
        float acc[8];
        #pragma unroll
        for (int r = 0; r < 8; ++r) acc[r] = 0.f;

        #pragma unroll
        for (int k = 0; k < 3; ++k) {
            int d4 = lane + 64 * k;
            float4 tv = tok4[d4];
            #pragma unroll
            for (int r = 0; r < 8; ++r) {
                float4 ar = *(const float4*)(As + r * 768 + d4 * 4);
                acc[r] += tv.x * ar.x + tv.y * ar.y + tv.z * ar.z + tv.w * ar.w;
            }
        }

        #pragma unroll
        for (int off = 32; off > 0; off >>= 1) {
            #pragma unroll
            for (int r = 0; r < 8; ++r)
                acc[r] += __shfl_xor(acc[r], off, 64);
        }

        if (lane == 0) {
            float4 h0, h1;
            h0.x = acc[0] * gs; h0.y = acc[1] * gs; h0.z = acc[2] * gs; h0.w = acc[3] * gs;
            h1.x = acc[4] * gs; h1.y = acc[5] * gs; h1.z = acc[6] * gs; h1.w = acc[7] * gs;
            float4* hp = (float4*)(hws + ((long long)b * T_ + t) * 8);
            hp[0] = h0;
            hp[1] = h1;
        }
    }
}

// ---------------------------------------------------------------------------
// Kernel 5: weighted_update = h @ Bw[sel].  Bw in LDS (72 KB → 2 blocks/CU).
// Pure write-bound pass: 232 MB of nontemporal float4 stores, contiguous
// rows per wave.
// ---------------------------------------------------------------------------
__global__ void __launch_bounds__(256, 2)
lora_out(const float* __restrict__ hws,
         const float* __restrict__ lora_b,
         const float* __restrict__ outc,
         float* __restrict__ out) {
    __shared__ __align__(16) float Bw_s[8 * 2304];   // 72 KB

    int chunk = blockIdx.x;
    int b     = blockIdx.y;
    int tid   = threadIdx.x;

    int sel = (int)outc[OFF_SEL + b];

    const float4* Bw4g = (const float4*)(lora_b + (long long)sel * 8 * 2304);
    float4*       Bw4s = (float4*)Bw_s;
    for (int i = tid; i < 8 * 576; i += 256) Bw4s[i] = Bw4g[i];
    __syncthreads();

    int wave = tid >> 6;
    int lane = tid & 63;
    int t0 = chunk * 50;
    int t1 = t0 + 50; if (t1 > T_) t1 = T_;
    int nr  = t1 - t0;
    int rpw = (nr + 3) >> 2;
    int ts  = t0 + wave * rpw;
    int te  = ts + rpw; if (te > t1) te = t1;

    for (int t = ts; t < te; ++t) {
        const float4* hp = (const float4*)(hws + ((long long)b * T_ + t) * 8);
        float4 h0 = hp[0];
        float4 h1 = hp[1];

        v4f* outrow = (v4f*)(out + ((long long)b * T_ + t) * O_);
        #pragma unroll
        for (int k = 0; k < 9; ++k) {
            int o4 = lane + 64 * k;
            const float4* B0 = (const float4*)(Bw_s + 0 * 2304) + o4;
            v4f v;
            float4 bv;
            bv = B0[0 * 576]; v.x  = h0.x * bv.x; v.y  = h0.x * bv.y; v.z  = h0.x * bv.z; v.w  = h0.x * bv.w;
            bv = B0[1 * 576]; v.x += h0.y * bv.x; v.y += h0.y * bv.y; v.z += h0.y * bv.z; v.w += h0.y * bv.w;
            bv = B0[2 * 576]; v.x += h0.z * bv.x; v.y += h0.z * bv.y; v.z += h0.z * bv.z; v.w += h0.z * bv.w;
            bv = B0[3 * 576]; v.x += h0.w * bv.x; v.y += h0.w * bv.y; v.z += h0.w * bv.z; v.w += h0.w * bv.w;
            bv = B0[4 * 576]; v.x += h1.x * bv.x; v.y += h1.x * bv.y; v.z += h1.x * bv.z; v.w += h1.x * bv.w;
            bv = B0[5 * 576]; v.x += h1.y * bv.x; v.y += h1.y * bv.y; v.z += h1.y * bv.z; v.w += h1.y * bv.w;
            bv = B0[6 * 576]; v.x += h1.z * bv.x; v.y += h1.z * bv.y; v.z += h1.z * bv.z; v.w += h1.z * bv.w;
            bv = B0[7 * 576]; v.x += h1.w * bv.x; v.y += h1.w * bv.y; v.z += h1.w * bv.z; v.w += h1.w * bv.w;
            __builtin_nontemporal_store(v, &outrow[o4]);
        }
    }
}

// ---------------------------------------------------------------------------
extern "C" void kernel_launch(void* const* d_in, const int* in_sizes, int n_in,
                              void* d_out, int out_size, void* d_ws, size_t ws_size,
                              hipStream_t stream) {
    const float* tokens  = (const float*)d_in[0];
    const float* w_gate  = (const float*)d_in[1];
    const float* lora_a  = (const float*)d_in[2];
    const float* lora_b  = (const float*)d_in[3];
    const float* scaling = (const float*)d_in[4];
    float* out = (float*)d_out;
    float* hws = (float*)d_ws;     // needs 128*197*8*4 B = 807 KB

    pool_partial<<<dim3(4, 128), 192, 0, stream>>>(tokens, out);
    route<<<128, 256, 0, stream>>>(out, w_gate, out);
    stats<<<1, 128, 0, stream>>>(out);
    lora_h<<<dim3(4, 128), 256, 0, stream>>>(tokens, lora_a, scaling, out, hws);
    lora_out<<<dim3(4, 128), 256, 0, stream>>>(hws, lora_b, out, out);
}